// Round 2
// baseline (81.397 us; speedup 1.0000x reference)
//
#include <hip/hip_runtime.h>

// Problem constants
#define B_    8
#define C_    512
#define T_    512
#define O_    512
#define K_    65
#define PAD_  32

// Tiling: 8 waves/block, each wave owns J_=4 outputs x all 128 t (2 t/lane).
// x is read DIRECTLY from global (L2/L3-resident, wave-uniform rows, 512B/wave
// coalesced) -- no x LDS staging, no staging barrier. LDS holds only the banded
// weight table (8.7 KB) + y transpose tile (18.4 KB) = 27.1 KB -> 4 blocks/CU,
// 8 waves/SIMD (2x round-1 TLP).
#define O_TILE 32
#define T_TILE 128
#define J_     4
#define NWAVE  8
#define NTHR   512
#define NR_    (J_ + 2 * PAD_)       // 68 banded steps per output group
#define YPITCH 36

#define WT_TILE (NWAVE * NR_ * J_)   // 2176 floats (8.7 KB)
#define YT_ELEMS (T_TILE * YPITCH)   // 4608 floats (18.4 KB)

// Row-keyed XOR swizzle for the y tile: colliding writer lanes (rows differing
// by 8 at stride 36) get distinct 4-float slots -> 16-way conflict becomes 2-way.
#define YSWZ(row) ((((row) >> 3) & 7) << 2)

__global__ __launch_bounds__(NTHR, 8)
void conv_fused(const float* __restrict__ x,
                const float* __restrict__ w,
                const float* __restrict__ bias,
                float* __restrict__ out) {
    __shared__ float smem[WT_TILE + YT_ELEMS];
    float* wts = smem;
    float* ys  = smem + WT_TILE;

    const int tid = threadIdx.x;
    const int bid = blockIdx.x;          // 512: b(8) x ob(16) x tb(4)
    const int b   = bid >> 6;
    const int rem = bid & 63;
    const int ob  = rem >> 2;
    const int tb  = rem & 3;
    const int t0  = tb * T_TILE;

    // ---- Stage banded weight table: wts[g][r][j] = W[(ob*8+g)*4+j][r-j] ----
    {
        #pragma unroll
        for (int p = 0; p < (WT_TILE + NTHR - 1) / NTHR; ++p) {   // 5 iters
            const int e = p * NTHR + tid;
            if (e < WT_TILE) {
                const int g  = e / (NR_ * J_);
                const int r2 = e % (NR_ * J_);
                const int r  = r2 >> 2;
                const int j  = r2 & 3;
                const int o  = (ob * NWAVE + g) * J_ + j;
                const int k  = r - j;
                float v = 0.f;
                if (k >= 0 && k < K_) v = w[o * K_ + k];
                wts[e] = v;
            }
        }
    }
    __syncthreads();

    // ---- Compute: wave wu -> outputs [obase, obase+4), lane -> t pair ----
    const int lane = tid & 63;
    const int wu   = __builtin_amdgcn_readfirstlane(tid >> 6);  // uniform 0..7
    const int obase = ob * O_TILE + wu * J_;

    float2 acc[J_];
    #pragma unroll
    for (int j = 0; j < J_; ++j) {
        const float bj = bias[obase + j];   // uniform -> scalar load
        acc[j] = make_float2(bj, bj);
    }

    const int tl = lane * 2;
    const float* xg = x + (size_t)b * (C_ * T_) + t0 + tl;
    const float4* wrow = (const float4*)(wts) + wu * NR_;   // uniform addr -> LDS broadcast
    const int c0 = obase - PAD_;                            // uniform first x row

    if (c0 >= 0 && c0 + NR_ - 1 < C_) {
        // Interior: unguarded loads, max MLP
        #pragma unroll 4
        for (int r = 0; r < NR_; ++r) {
            const float2 xv = *(const float2*)(xg + (size_t)(c0 + r) * T_);
            const float4 wv = wrow[r];
            acc[0].x += wv.x * xv.x;  acc[0].y += wv.x * xv.y;
            acc[1].x += wv.y * xv.x;  acc[1].y += wv.y * xv.y;
            acc[2].x += wv.z * xv.x;  acc[2].y += wv.z * xv.y;
            acc[3].x += wv.w * xv.x;  acc[3].y += wv.w * xv.y;
        }
    } else {
        // Edge blocks (ob==0 / ob==15): wave-uniform scalar guard per row
        #pragma unroll 4
        for (int r = 0; r < NR_; ++r) {
            const int c = c0 + r;
            float2 xv = make_float2(0.f, 0.f);
            if (c >= 0 && c < C_)
                xv = *(const float2*)(xg + (size_t)c * T_);
            const float4 wv = wrow[r];
            acc[0].x += wv.x * xv.x;  acc[0].y += wv.x * xv.y;
            acc[1].x += wv.y * xv.x;  acc[1].y += wv.y * xv.y;
            acc[2].x += wv.z * xv.x;  acc[2].y += wv.z * xv.y;
            acc[3].x += wv.w * xv.x;  acc[3].y += wv.w * xv.y;
        }
    }

    // ---- Transpose through LDS (no barrier needed before: ys is private-write) ----
    {
        const int olb = wu * J_;
        const int r0 = tl, r1 = tl + 1;
        *(float4*)(&ys[r0 * YPITCH + (olb ^ YSWZ(r0))]) =
            make_float4(acc[0].x, acc[1].x, acc[2].x, acc[3].x);
        *(float4*)(&ys[r1 * YPITCH + (olb ^ YSWZ(r1))]) =
            make_float4(acc[0].y, acc[1].y, acc[2].y, acc[3].y);
    }
    __syncthreads();

    // ---- Coalesced global store ----
    {
        float* ob_out = out + (size_t)b * (T_ * O_) + (size_t)t0 * O_ + ob * O_TILE;
        const int ol   = (tid & 7) * 4;
        const int trow = tid >> 3;          // 0..63
        #pragma unroll
        for (int p = 0; p < 2; ++p) {
            const int t_local = p * 64 + trow;
            const float4 v = *(const float4*)(&ys[t_local * YPITCH + (ol ^ YSWZ(t_local))]);
            *(float4*)(ob_out + (size_t)t_local * O_ + ol) = v;
        }
    }
}

extern "C" void kernel_launch(void* const* d_in, const int* in_sizes, int n_in,
                              void* d_out, int out_size, void* d_ws, size_t ws_size,
                              hipStream_t stream) {
    const float* x    = (const float*)d_in[0];
    const float* w    = (const float*)d_in[1];
    const float* bias = (const float*)d_in[2];
    float* out = (float*)d_out;
    (void)d_ws; (void)ws_size;   // workspace unused (256 MiB poison fill is unconditional)

    const int nblocks = B_ * (O_ / O_TILE) * (T_ / T_TILE);   // 512
    conv_fused<<<nblocks, NTHR, 0, stream>>>(x, w, bias, out);
}

// Round 3
// 72.809 us; speedup vs baseline: 1.1180x; 1.1180x over previous
//
#include <hip/hip_runtime.h>

// Problem constants
#define B_    8
#define C_    512
#define T_    512
#define O_    512
#define K_    65
#define PAD_  32

// Round-1 structure (x staged in LDS -- proven 8us faster than direct-global)
// + separate y tile (drops the compute->transpose barrier)
// + XOR-swizzled y transpose (4-way -> 2-way write conflict).
// LDS = 48 KB (x) + 8.7 KB (wt) + 18 KB (y) = 74.5 KB -> 2 blocks/CU,
// 16 waves/CU = 4 waves/SIMD.
#define O_TILE 32
#define T_TILE 128
#define J_     4
#define NWAVE  8
#define NTHR   512
#define ROWS   (O_TILE + 2 * PAD_)   // 96 x-rows staged
#define NR_    (J_ + 2 * PAD_)       // 68 banded steps per output group
#define YPITCH 36

#define XTILE_ELEMS (ROWS * T_TILE)      // 12288 floats (48 KB)
#define WT_TILE     (NWAVE * NR_ * J_)   // 2176 floats (8.7 KB)
#define YT_ELEMS    (T_TILE * YPITCH)    // 4608 floats (18.4 KB)

// Row-keyed XOR swizzle for the y tile (applied on write and read):
// maps colliding writer lanes (rows differing by 32 at pitch 36) to
// distinct float4 slots. Result stays in [0, 32) -> within pitch.
#define YSWZ(row) ((((row) >> 3) & 7) << 2)

__global__ __launch_bounds__(NTHR, 4)
void conv_fused(const float* __restrict__ x,
                const float* __restrict__ w,
                const float* __restrict__ bias,
                float* __restrict__ out) {
    __shared__ float smem[XTILE_ELEMS + WT_TILE + YT_ELEMS];
    float* xs  = smem;
    float* wts = smem + XTILE_ELEMS;
    float* ys  = smem + XTILE_ELEMS + WT_TILE;

    const int tid = threadIdx.x;
    const int bid = blockIdx.x;          // 512: b(8) x ob(16) x tb(4)
    const int b   = bid >> 6;
    const int rem = bid & 63;
    const int ob  = rem >> 2;
    const int tb  = rem & 3;
    const int t0  = tb * T_TILE;
    const int c_base = ob * O_TILE - PAD_;

    // ---- Stage x tile (96 rows x 128 cols, zero-padded rows outside [0,C)) ----
    {
        const float* xb = x + (size_t)b * (C_ * T_);
        const int l32 = tid & 31;        // col group (float4)
        const int rg  = tid >> 5;        // 0..15 row group
        if (c_base >= 0 && c_base + ROWS <= C_) {
            // Interior ob tiles (14 of 16): unguarded
            #pragma unroll
            for (int rr = 0; rr < ROWS / 16; ++rr) {   // 6 iters
                const int row = rr * 16 + rg;
                const float4 v = *(const float4*)(xb + (c_base + row) * T_ + t0 + l32 * 4);
                *(float4*)(&xs[row * T_TILE + l32 * 4]) = v;
            }
        } else {
            #pragma unroll
            for (int rr = 0; rr < ROWS / 16; ++rr) {
                const int row = rr * 16 + rg;
                const int c   = c_base + row;
                float4 v = make_float4(0.f, 0.f, 0.f, 0.f);
                if (c >= 0 && c < C_)
                    v = *(const float4*)(xb + c * T_ + t0 + l32 * 4);
                *(float4*)(&xs[row * T_TILE + l32 * 4]) = v;
            }
        }
    }

    // ---- Stage banded weight table: wts[g][r][j] = W[(ob*8+g)*4+j][r-j] ----
    {
        #pragma unroll
        for (int p = 0; p < (WT_TILE + NTHR - 1) / NTHR; ++p) {   // 5 iters
            const int e = p * NTHR + tid;
            if (e < WT_TILE) {
                const int g  = e / (NR_ * J_);
                const int r2 = e % (NR_ * J_);
                const int r  = r2 >> 2;
                const int j  = r2 & 3;
                const int o  = (ob * NWAVE + g) * J_ + j;
                const int k  = r - j;
                float v = 0.f;
                if (k >= 0 && k < K_) v = w[o * K_ + k];
                wts[e] = v;
            }
        }
    }
    __syncthreads();

    // ---- Compute: wave wu -> outputs [obase, obase+4), lane -> t pair ----
    const int lane = tid & 63;
    const int wu   = __builtin_amdgcn_readfirstlane(tid >> 6);  // uniform 0..7
    const int obase = ob * O_TILE + wu * J_;

    float2 acc[J_];
    #pragma unroll
    for (int j = 0; j < J_; ++j) {
        const float bj = bias[obase + j];   // uniform -> scalar load
        acc[j] = make_float2(bj, bj);
    }

    const int tl = lane * 2;
    const float* xrow = xs + (wu * J_) * T_TILE + tl;
    const float4* wrow = (const float4*)(wts) + wu * NR_;   // uniform -> LDS broadcast

    #pragma unroll 4
    for (int r = 0; r < NR_; ++r) {
        const float2 xv = *(const float2*)(xrow + r * T_TILE);
        const float4 wv = wrow[r];
        acc[0].x += wv.x * xv.x;  acc[0].y += wv.x * xv.y;
        acc[1].x += wv.y * xv.x;  acc[1].y += wv.y * xv.y;
        acc[2].x += wv.z * xv.x;  acc[2].y += wv.z * xv.y;
        acc[3].x += wv.w * xv.x;  acc[3].y += wv.w * xv.y;
    }

    // ---- Transpose through LDS (ys disjoint from xs/wts; writes are
    //      thread-private slots -> no barrier needed before) ----
    {
        const int olb = wu * J_;
        const int r0 = tl, r1 = tl + 1;
        *(float4*)(&ys[r0 * YPITCH + (olb ^ YSWZ(r0))]) =
            make_float4(acc[0].x, acc[1].x, acc[2].x, acc[3].x);
        *(float4*)(&ys[r1 * YPITCH + (olb ^ YSWZ(r1))]) =
            make_float4(acc[0].y, acc[1].y, acc[2].y, acc[3].y);
    }
    __syncthreads();

    // ---- Coalesced global store ----
    {
        float* ob_out = out + (size_t)b * (T_ * O_) + (size_t)t0 * O_ + ob * O_TILE;
        const int ol   = (tid & 7) * 4;
        const int trow = tid >> 3;          // 0..63
        #pragma unroll
        for (int p = 0; p < 2; ++p) {
            const int t_local = p * 64 + trow;
            const float4 v = *(const float4*)(&ys[t_local * YPITCH + (ol ^ YSWZ(t_local))]);
            *(float4*)(ob_out + (size_t)t_local * O_ + ol) = v;
        }
    }
}

extern "C" void kernel_launch(void* const* d_in, const int* in_sizes, int n_in,
                              void* d_out, int out_size, void* d_ws, size_t ws_size,
                              hipStream_t stream) {
    const float* x    = (const float*)d_in[0];
    const float* w    = (const float*)d_in[1];
    const float* bias = (const float*)d_in[2];
    float* out = (float*)d_out;
    (void)d_ws; (void)ws_size;   // workspace unused (256 MiB poison fill is unconditional)

    const int nblocks = B_ * (O_ / O_TILE) * (T_ / T_TILE);   // 512
    conv_fused<<<nblocks, NTHR, 0, stream>>>(x, w, bias, out);
}